// Round 2
// 473.576 us; speedup vs baseline: 1.0333x; 1.0333x over previous
//
#include <hip/hip_runtime.h>

// LSTM2: B=8192, T=60, F=158, H=32, 2 layers, head on final cell states.
// R5b: skewed 2-barrier pipeline — layer-1 gates(t+1) and layer-2 gates(t) are
// mutually independent (both need only h1(t), h2(t-1), x(t+1)), so they run in
// ONE MFMA phase (48 MFMAs, 8 independent acc chains), then ONE barrier, both
// cell updates, ONE barrier.  4 -> 2 barriers/step.
// Numerics: f16 hi/lo limb split (more accurate than bf16 hi/lo: ~2^-21).
// Lo limbs are scaled by 2^12 so they stay in f16 NORMAL range; lo products
// accumulate in a separate MFMA accumulator and are recombined with an exact
// power-of-2 FMA at gate store.  v_cvt_pkrtz packs 2 floats/instr (~3x fewer
// VALU ops than round-to-bf16 staging).
// NOTE: cvt_pkrtz returns an __fp16 vector; MFMA frags are _Float16 vectors —
// keep two typedefs and cast element-wise (fixed from R5 compile failure).

constexpr int Bn = 8192, Tn = 60, Fn = 158, Hn = 32;
constexpr int SKX = 168;  // x-buffer short stride per row (160 + 8 pad)
constexpr int SKH = 40;   // h-buffer short stride per row
constexpr int SG = 132;   // gate scratch float stride per row (128 + 4 pad)
constexpr float LS = 4096.f;        // lo-limb scale (2^12)
constexpr float ILS = 1.f / 4096.f; // exact inverse

typedef _Float16 half8 __attribute__((ext_vector_type(8)));
typedef __fp16 half2f __attribute__((ext_vector_type(2)));  // cvt_pkrtz result
typedef __attribute__((ext_vector_type(4))) float floatx4;

__device__ __forceinline__ float sigm_(float x) {
    return __fdividef(1.f, 1.f + __expf(-x));
}
__device__ __forceinline__ float tanh_(float x) {
    return 1.f - __fdividef(2.f, __expf(2.f * x) + 1.f);
}
__device__ __forceinline__ unsigned h2u(half2f h) {
    return __builtin_bit_cast(unsigned, h);
}
// split 8 floats into f16 hi + 2^12-scaled f16 lo limbs
__device__ __forceinline__ void cvt8h(const float* v, half8& hi, half8& lo) {
#pragma unroll
    for (int j = 0; j < 8; j += 2) {
        half2f h = __builtin_amdgcn_cvt_pkrtz(v[j], v[j + 1]);
        float r0 = (v[j] - (float)h[0]) * LS;
        float r1 = (v[j + 1] - (float)h[1]) * LS;
        half2f l = __builtin_amdgcn_cvt_pkrtz(r0, r1);
        hi[j] = (_Float16)h[0]; hi[j + 1] = (_Float16)h[1];
        lo[j] = (_Float16)l[0]; lo[j + 1] = (_Float16)l[1];
    }
}

__global__ __launch_bounds__(256, 2) void lstm2_fused_kernel(
    const float* __restrict__ x,
    const float* __restrict__ Wih0, const float* __restrict__ Whh0,
    const float* __restrict__ Wih1, const float* __restrict__ Whh1,
    const float* __restrict__ W1, const float* __restrict__ b1,
    const float* __restrict__ W2, float* __restrict__ out) {
    __shared__ unsigned short sXh[2 * 16 * SKX];  // 10752 B
    __shared__ unsigned short sXl[2 * 16 * SKX];  // 10752 B
    __shared__ unsigned short sH1h[16 * SKH], sH1l[16 * SKH];  // 1280 B each
    __shared__ unsigned short sH2h[16 * SKH], sH2l[16 * SKH];
    __shared__ float sG1[16 * SG];  // 8448 B, layer-1 gates (t+1); head scratch
    __shared__ float sG2[16 * SG];  // 8448 B, layer-2 gates (t)

    const int tid = threadIdx.x;
    const int wave = tid >> 6, lane = tid & 63;
    const int quad = lane >> 4, l15 = lane & 15;
    const int bBase = blockIdx.x * 16;

    // ---- register B-fragments (f16 hi + scaled-lo) --------------------------
    // Wih0: [128 gates][158] -> bX[ks][nt][hi/lo], k = ks*32 + quad*8 + j
    half8 bX[5][2][2];
#pragma unroll
    for (int nt = 0; nt < 2; ++nt) {
        const int n = wave * 32 + nt * 16 + l15;
#pragma unroll
        for (int ks = 0; ks < 5; ++ks) {
            float wv[8];
#pragma unroll
            for (int j = 0; j < 8; ++j) {
                int k = ks * 32 + quad * 8 + j;
                wv[j] = (k < Fn) ? Wih0[n * Fn + k] : 0.f;
            }
            cvt8h(wv, bX[ks][nt][0], bX[ks][nt][1]);
        }
    }
    // recurrent: 0=Whh0, 1=Wih1, 2=Whh1 (each [128][32])
    half8 bW[3][2][2];
    const float* Wp[3] = {Whh0, Wih1, Whh1};
#pragma unroll
    for (int m = 0; m < 3; ++m)
#pragma unroll
        for (int nt = 0; nt < 2; ++nt) {
            const int n = wave * 32 + nt * 16 + l15;
            const float* wp = Wp[m] + n * Hn + quad * 8;
            float4 q0 = *(const float4*)(wp);
            float4 q1 = *(const float4*)(wp + 4);
            float wv[8] = {q0.x, q0.y, q0.z, q0.w, q1.x, q1.y, q1.z, q1.w};
            cvt8h(wv, bW[m][nt][0], bW[m][nt][1]);
        }

    // ---- x staging map: 16 rows x 79 float2, 5 per thread -------------------
    const float* xp[5];
    int soff[5];
    bool act[5];
#pragma unroll
    for (int r = 0; r < 5; ++r) {
        int i = tid + r * 256;
        act[r] = (i < 1264);
        int row = i / 79, c = i - row * 79;
        if (!act[r]) { row = 0; c = 0; }
        soff[r] = row * (SKX / 2) + c;
        xp[r] = x + (size_t)(bBase + row) * (Tn * Fn) + 2 * c;
    }
    auto stage = [&](const float2* v, int buf) {
        unsigned* dh = (unsigned*)sXh + buf * (16 * SKX / 2);
        unsigned* dl = (unsigned*)sXl + buf * (16 * SKX / 2);
#pragma unroll
        for (int r = 0; r < 5; ++r) {
            if (act[r]) {
                half2f h = __builtin_amdgcn_cvt_pkrtz(v[r].x, v[r].y);
                half2f l = __builtin_amdgcn_cvt_pkrtz(
                    (v[r].x - (float)h[0]) * LS, (v[r].y - (float)h[1]) * LS);
                dh[soff[r]] = h2u(h);
                dl[soff[r]] = h2u(l);
            }
        }
    };

    // zero h state, zero x pad columns (k=158,159) in both buffers
    for (int i = tid; i < 320; i += 256) {
        ((unsigned*)sH1h)[i] = 0; ((unsigned*)sH1l)[i] = 0;
        ((unsigned*)sH2h)[i] = 0; ((unsigned*)sH2l)[i] = 0;
    }
    if (tid < 32) {
        int buf = tid >> 4, row = tid & 15;
        ((unsigned*)sXh)[buf * 1344 + row * 84 + 79] = 0;
        ((unsigned*)sXl)[buf * 1344 + row * 84 + 79] = 0;
    }

    // stage x(0) -> buf0, x(1) -> buf1
#pragma unroll
    for (int t0 = 0; t0 < 2; ++t0) {
        float2 v[5];
#pragma unroll
        for (int r = 0; r < 5; ++r) {
            v[r] = act[r] ? *(const float2*)xp[r] : make_float2(0.f, 0.f);
            xp[r] += Fn;
        }
        stage(v, t0);
    }

    const int aOffH = l15 * SKH + quad * 8;          // h A-frag short offset
    const int urow = tid >> 4, hp = (tid & 15) * 2;  // update mapping
    float c1x = 0.f, c1y = 0.f, c2x = 0.f, c2y = 0.f;

    // cell update: gates at [row][h][i,f,g,o]; writes h limbs to LDS
    auto upd = [&](const float* sGx, unsigned short* sHh, unsigned short* sHl,
                   float& cx, float& cy) {
        const float* g = sGx + urow * SG + hp * 4;
        float4 A = *(const float4*)g;        // i,f,g,o for h = hp
        float4 Bv = *(const float4*)(g + 4); // i,f,g,o for h = hp+1
        cx = sigm_(A.y) * cx + sigm_(A.x) * tanh_(A.z);
        cy = sigm_(Bv.y) * cy + sigm_(Bv.x) * tanh_(Bv.z);
        float h0 = sigm_(A.w) * tanh_(cx);
        float h1v = sigm_(Bv.w) * tanh_(cy);
        half2f hh = __builtin_amdgcn_cvt_pkrtz(h0, h1v);
        half2f hl = __builtin_amdgcn_cvt_pkrtz((h0 - (float)hh[0]) * LS,
                                               (h1v - (float)hh[1]) * LS);
        *(unsigned*)(sHh + urow * SKH + hp) = h2u(hh);
        *(unsigned*)(sHl + urow * SKH + hp) = h2u(hl);
    };

    __syncthreads();  // P1: x(0), x(1), zeros visible

    // ---- prologue: gates1(0) = x(0) @ Wih0^T (h1 = 0, h-part skipped) ------
    {
        floatx4 aH[2] = {}, aL[2] = {};
#pragma unroll
        for (int ks = 0; ks < 5; ++ks) {
            const int off = l15 * SKX + ks * 32 + quad * 8;
            half8 xh = *(const half8*)(sXh + off);
            half8 xl = *(const half8*)(sXl + off);
#pragma unroll
            for (int nt = 0; nt < 2; ++nt) {
                aH[nt] = __builtin_amdgcn_mfma_f32_16x16x32_f16(xh, bX[ks][nt][0], aH[nt], 0, 0, 0);
                aL[nt] = __builtin_amdgcn_mfma_f32_16x16x32_f16(xh, bX[ks][nt][1], aL[nt], 0, 0, 0);
                aL[nt] = __builtin_amdgcn_mfma_f32_16x16x32_f16(xl, bX[ks][nt][0], aL[nt], 0, 0, 0);
            }
        }
#pragma unroll
        for (int nt = 0; nt < 2; ++nt)
#pragma unroll
            for (int reg = 0; reg < 4; ++reg)
                sG1[(quad * 4 + reg) * SG + (nt * 16 + l15) * 4 + wave] =
                    fmaf(ILS, aL[nt][reg], aH[nt][reg]);
    }
    __syncthreads();  // P2: gates1(0) visible
    upd(sG1, sH1h, sH1l, c1x, c1y);  // -> h1(0), c1(0)
    __syncthreads();  // P3: h1(0) visible

    // ---- main skewed loop: iter i computes gates1(i+1) & gates2(i) ---------
    for (int i = 0; i < Tn - 1; ++i) {
        float2 xr[5];
        const bool pf = (i + 2 < Tn);
        if (pf) {
#pragma unroll
            for (int r = 0; r < 5; ++r) {
                xr[r] = act[r] ? *(const float2*)xp[r] : make_float2(0.f, 0.f);
                xp[r] += Fn;
            }
        }
        {
            const unsigned short* bxh = sXh + ((i + 1) & 1) * (16 * SKX);
            const unsigned short* bxl = sXl + ((i + 1) & 1) * (16 * SKX);
            half8 a1h = *(const half8*)(sH1h + aOffH);
            half8 a1l = *(const half8*)(sH1l + aOffH);
            half8 a2h = *(const half8*)(sH2h + aOffH);
            half8 a2l = *(const half8*)(sH2l + aOffH);
            floatx4 a1H[2] = {}, a1L[2] = {}, a2H[2] = {}, a2L[2] = {};
#pragma unroll
            for (int ks = 0; ks < 5; ++ks) {
                const int off = l15 * SKX + ks * 32 + quad * 8;
                half8 xh = *(const half8*)(bxh + off);
                half8 xl = *(const half8*)(bxl + off);
#pragma unroll
                for (int nt = 0; nt < 2; ++nt) {
                    a1H[nt] = __builtin_amdgcn_mfma_f32_16x16x32_f16(xh, bX[ks][nt][0], a1H[nt], 0, 0, 0);
                    a1L[nt] = __builtin_amdgcn_mfma_f32_16x16x32_f16(xh, bX[ks][nt][1], a1L[nt], 0, 0, 0);
                    a1L[nt] = __builtin_amdgcn_mfma_f32_16x16x32_f16(xl, bX[ks][nt][0], a1L[nt], 0, 0, 0);
                }
            }
#pragma unroll
            for (int nt = 0; nt < 2; ++nt) {
                a1H[nt] = __builtin_amdgcn_mfma_f32_16x16x32_f16(a1h, bW[0][nt][0], a1H[nt], 0, 0, 0);
                a1L[nt] = __builtin_amdgcn_mfma_f32_16x16x32_f16(a1h, bW[0][nt][1], a1L[nt], 0, 0, 0);
                a1L[nt] = __builtin_amdgcn_mfma_f32_16x16x32_f16(a1l, bW[0][nt][0], a1L[nt], 0, 0, 0);
                a2H[nt] = __builtin_amdgcn_mfma_f32_16x16x32_f16(a1h, bW[1][nt][0], a2H[nt], 0, 0, 0);
                a2L[nt] = __builtin_amdgcn_mfma_f32_16x16x32_f16(a1h, bW[1][nt][1], a2L[nt], 0, 0, 0);
                a2L[nt] = __builtin_amdgcn_mfma_f32_16x16x32_f16(a1l, bW[1][nt][0], a2L[nt], 0, 0, 0);
                a2H[nt] = __builtin_amdgcn_mfma_f32_16x16x32_f16(a2h, bW[2][nt][0], a2H[nt], 0, 0, 0);
                a2L[nt] = __builtin_amdgcn_mfma_f32_16x16x32_f16(a2h, bW[2][nt][1], a2L[nt], 0, 0, 0);
                a2L[nt] = __builtin_amdgcn_mfma_f32_16x16x32_f16(a2l, bW[2][nt][0], a2L[nt], 0, 0, 0);
            }
#pragma unroll
            for (int nt = 0; nt < 2; ++nt)
#pragma unroll
                for (int reg = 0; reg < 4; ++reg) {
                    const int idx = (quad * 4 + reg) * SG + (nt * 16 + l15) * 4 + wave;
                    sG1[idx] = fmaf(ILS, a1L[nt][reg], a1H[nt][reg]);
                    sG2[idx] = fmaf(ILS, a2L[nt][reg], a2H[nt][reg]);
                }
        }
        if (pf) stage(xr, i & 1);  // x(i+2) -> buf[(i+2)&1]; last read x(i), 2 barriers ago
        __syncthreads();  // B1: gates + staged x visible; h reads done
        upd(sG2, sH2h, sH2l, c2x, c2y);  // step i   layer 2 -> h2(i)
        upd(sG1, sH1h, sH1l, c1x, c1y);  // step i+1 layer 1 -> h1(i+1)
        __syncthreads();  // B2: new h visible; gate reads done
    }

    // ---- epilogue: gates2(T-1), final layer-2 update (c only) --------------
    {
        half8 a1h = *(const half8*)(sH1h + aOffH);
        half8 a1l = *(const half8*)(sH1l + aOffH);
        half8 a2h = *(const half8*)(sH2h + aOffH);
        half8 a2l = *(const half8*)(sH2l + aOffH);
        floatx4 aH[2] = {}, aL[2] = {};
#pragma unroll
        for (int nt = 0; nt < 2; ++nt) {
            aH[nt] = __builtin_amdgcn_mfma_f32_16x16x32_f16(a1h, bW[1][nt][0], aH[nt], 0, 0, 0);
            aL[nt] = __builtin_amdgcn_mfma_f32_16x16x32_f16(a1h, bW[1][nt][1], aL[nt], 0, 0, 0);
            aL[nt] = __builtin_amdgcn_mfma_f32_16x16x32_f16(a1l, bW[1][nt][0], aL[nt], 0, 0, 0);
            aH[nt] = __builtin_amdgcn_mfma_f32_16x16x32_f16(a2h, bW[2][nt][0], aH[nt], 0, 0, 0);
            aL[nt] = __builtin_amdgcn_mfma_f32_16x16x32_f16(a2h, bW[2][nt][1], aL[nt], 0, 0, 0);
            aL[nt] = __builtin_amdgcn_mfma_f32_16x16x32_f16(a2l, bW[2][nt][0], aL[nt], 0, 0, 0);
        }
#pragma unroll
        for (int nt = 0; nt < 2; ++nt)
#pragma unroll
            for (int reg = 0; reg < 4; ++reg)
                sG2[(quad * 4 + reg) * SG + (nt * 16 + l15) * 4 + wave] =
                    fmaf(ILS, aL[nt][reg], aH[nt][reg]);
    }
    __syncthreads();
    {
        const float* g = sG2 + urow * SG + hp * 4;
        float4 A = *(const float4*)g;
        float4 Bv = *(const float4*)(g + 4);
        c2x = sigm_(A.y) * c2x + sigm_(A.x) * tanh_(A.z);
        c2y = sigm_(Bv.y) * c2y + sigm_(Bv.x) * tanh_(Bv.z);
    }

    // ---- head on final c1, c2: y = relu(c @ W1^T + b1) @ W2^T --------------
    float* sC = sG1;  // [2][16][33]
    *(float2*)(sC + urow * 33 + hp) = make_float2(c1x, c1y);
    *(float2*)(sC + 528 + urow * 33 + hp) = make_float2(c2x, c2y);
    __syncthreads();
    if (tid < 32) {
        int l = tid >> 4, b = tid & 15;
        const float* cc = sC + l * 528 + b * 33;
        float y = 0.f;
#pragma unroll 1
        for (int q = 0; q < 16; ++q) {
            float s = b1[q];
#pragma unroll
            for (int j = 0; j < 32; ++j) s = fmaf(cc[j], W1[q * 32 + j], s);
            y = fmaf(fmaxf(s, 0.f), W2[q], y);
        }
        out[l * Bn + bBase + b] = y;
    }
}

extern "C" void kernel_launch(void* const* d_in, const int* in_sizes, int n_in,
                              void* d_out, int out_size, void* d_ws, size_t ws_size,
                              hipStream_t stream) {
    const float* x    = (const float*)d_in[0];
    const float* Wih0 = (const float*)d_in[1];
    const float* Whh0 = (const float*)d_in[2];
    const float* Wih1 = (const float*)d_in[3];
    const float* Whh1 = (const float*)d_in[4];
    const float* W1   = (const float*)d_in[5];
    const float* b1   = (const float*)d_in[6];
    const float* W2   = (const float*)d_in[7];
    float* out = (float*)d_out;

    lstm2_fused_kernel<<<Bn / 16, 256, 0, stream>>>(x, Wih0, Whh0, Wih1, Whh1,
                                                    W1, b1, W2, out);
}

// Round 3
// 461.834 us; speedup vs baseline: 1.0596x; 1.0254x over previous
//
#include <hip/hip_runtime.h>

// LSTM2: B=8192, T=60, F=158, H=32, 2 layers, head on final cell states.
// R6: operand-swapped MFMA -> fully in-register cell update.
//   A = weights (M=gate rows, row-permuted r = hidden_local*4 + gate),
//   B = activations (N=batch). D layout (row=quad*4+reg, col=l15) then gives
//   acc[reg] = (i,f,g,o)[reg] for hidden h = wave*8+mt*4+quad, batch b=l15:
//   the whole cell update is register-resident. No gate LDS round-trip
//   (R5b's 2.06e7 bank-conflict cycles came from the conflicted float4 gate
//   reads), and only ONE barrier per timestep. Only h (16x32, hi/lo limbs)
//   crosses LDS, double-buffered by parity: b16 scatter writes, b128 reads.
//   The x B-fragment address pattern is identical to the old A-fragment, so
//   x staging (f16 hi + 2^12-scaled lo limbs, cvt_pkrtz) is unchanged.
// Skew kept: iteration i computes gates1(i+1) and gates2(i) in one 48-MFMA
// phase (8 independent accumulator chains).

constexpr int Bn = 8192, Tn = 60, Fn = 158, Hn = 32;
constexpr int SKX = 168;  // x-buffer short stride per row (160 + 8 pad)
constexpr int SKH = 40;   // h-buffer short stride per row (16B-aligned)
constexpr float LS = 4096.f;        // lo-limb scale (2^12)
constexpr float ILS = 1.f / 4096.f; // exact inverse

typedef _Float16 half8 __attribute__((ext_vector_type(8)));
typedef __fp16 half2f __attribute__((ext_vector_type(2)));  // cvt_pkrtz result
typedef float floatx4 __attribute__((ext_vector_type(4)));

__device__ __forceinline__ float sigm_(float x) {
    return __fdividef(1.f, 1.f + __expf(-x));
}
__device__ __forceinline__ float tanh_(float x) {
    return 1.f - __fdividef(2.f, __expf(2.f * x) + 1.f);
}
__device__ __forceinline__ unsigned h2u(half2f h) {
    return __builtin_bit_cast(unsigned, h);
}
// split 8 floats into f16 hi + 2^12-scaled f16 lo limbs
__device__ __forceinline__ void cvt8h(const float* v, half8& hi, half8& lo) {
#pragma unroll
    for (int j = 0; j < 8; j += 2) {
        half2f h = __builtin_amdgcn_cvt_pkrtz(v[j], v[j + 1]);
        float r0 = (v[j] - (float)h[0]) * LS;
        float r1 = (v[j + 1] - (float)h[1]) * LS;
        half2f l = __builtin_amdgcn_cvt_pkrtz(r0, r1);
        hi[j] = (_Float16)h[0]; hi[j + 1] = (_Float16)h[1];
        lo[j] = (_Float16)l[0]; lo[j + 1] = (_Float16)l[1];
    }
}

__global__ __launch_bounds__(256, 2) void lstm2_fused_kernel(
    const float* __restrict__ x,
    const float* __restrict__ Wih0, const float* __restrict__ Whh0,
    const float* __restrict__ Wih1, const float* __restrict__ Whh1,
    const float* __restrict__ W1, const float* __restrict__ b1,
    const float* __restrict__ W2, float* __restrict__ out) {
    __shared__ unsigned short sXh[2 * 16 * SKX];  // 10752 B (x hi, dbuf)
    __shared__ unsigned short sXl[2 * 16 * SKX];  // 10752 B (x lo, dbuf)
    // h state: [parity][layer][limb][b*SKH + h]  (10240 B total)
    __shared__ unsigned short sH[2][2][2][16 * SKH];

    const int tid = threadIdx.x;
    const int wave = tid >> 6, lane = tid & 63;
    const int quad = lane >> 4, l15 = lane & 15;
    const int bBase = blockIdx.x * 16;
    const int hl = l15 >> 2, gi = l15 & 3;  // A-frag row r=l15 -> (hidden_local, gate)

    // ---- weights as A-fragments (f16 hi + scaled-lo), row-permuted ---------
    // tile row r covers gate row  gi*32 + (wave*8 + mt*4 + hl)
    half8 bX[5][2][2];  // Wih0 [ks][mt][limb], k = ks*32 + quad*8 + j
#pragma unroll
    for (int mt = 0; mt < 2; ++mt) {
        const int grow = gi * 32 + wave * 8 + mt * 4 + hl;
#pragma unroll
        for (int ks = 0; ks < 5; ++ks) {
            float wv[8];
#pragma unroll
            for (int j = 0; j < 8; ++j) {
                int k = ks * 32 + quad * 8 + j;
                wv[j] = (k < Fn) ? Wih0[grow * Fn + k] : 0.f;
            }
            cvt8h(wv, bX[ks][mt][0], bX[ks][mt][1]);
        }
    }
    half8 bW[3][2][2];  // 0=Whh0, 1=Wih1, 2=Whh1
    const float* Wp[3] = {Whh0, Wih1, Whh1};
#pragma unroll
    for (int m = 0; m < 3; ++m)
#pragma unroll
        for (int mt = 0; mt < 2; ++mt) {
            const int grow = gi * 32 + wave * 8 + mt * 4 + hl;
            const float* wp = Wp[m] + grow * Hn + quad * 8;
            float4 q0 = *(const float4*)(wp);
            float4 q1 = *(const float4*)(wp + 4);
            float wv[8] = {q0.x, q0.y, q0.z, q0.w, q1.x, q1.y, q1.z, q1.w};
            cvt8h(wv, bW[m][mt][0], bW[m][mt][1]);
        }

    // ---- x staging map: 16 rows x 79 float2, 5 per thread (unchanged) ------
    const float* xp[5];
    int soff[5];
    bool act[5];
#pragma unroll
    for (int r = 0; r < 5; ++r) {
        int i = tid + r * 256;
        act[r] = (i < 1264);
        int row = i / 79, c = i - row * 79;
        if (!act[r]) { row = 0; c = 0; }
        soff[r] = row * (SKX / 2) + c;
        xp[r] = x + (size_t)(bBase + row) * (Tn * Fn) + 2 * c;
    }
    auto stage = [&](const float2* v, int buf) {
        unsigned* dh = (unsigned*)sXh + buf * (16 * SKX / 2);
        unsigned* dl = (unsigned*)sXl + buf * (16 * SKX / 2);
#pragma unroll
        for (int r = 0; r < 5; ++r) {
            if (act[r]) {
                half2f h = __builtin_amdgcn_cvt_pkrtz(v[r].x, v[r].y);
                half2f l = __builtin_amdgcn_cvt_pkrtz(
                    (v[r].x - (float)h[0]) * LS, (v[r].y - (float)h[1]) * LS);
                dh[soff[r]] = h2u(h);
                dl[soff[r]] = h2u(l);
            }
        }
    };

    // zero all h buffers (only parity-0 h2 strictly needed), zero x pad cols
    for (int i = tid; i < 2560; i += 256) ((unsigned*)sH)[i] = 0;
    if (tid < 32) {
        int buf = tid >> 4, row = tid & 15;
        ((unsigned*)sXh)[buf * 1344 + row * 84 + 79] = 0;
        ((unsigned*)sXl)[buf * 1344 + row * 84 + 79] = 0;
    }

    // stage x(0) -> buf0, x(1) -> buf1
#pragma unroll
    for (int t0 = 0; t0 < 2; ++t0) {
        float2 v[5];
#pragma unroll
        for (int r = 0; r < 5; ++r) {
            v[r] = act[r] ? *(const float2*)xp[r] : make_float2(0.f, 0.f);
            xp[r] += Fn;
        }
        stage(v, t0);
    }

    const int hOffR = l15 * SKH + quad * 8;        // h B-frag read offset
    const int hW = l15 * SKH + wave * 8 + quad;    // h owner write (mt=0; +4 mt=1)
    float c1[2] = {0.f, 0.f}, c2[2] = {0.f, 0.f};

    // pack 2 h values (mt=0,1) into hi/lo limbs and scatter-store (b16 x4)
    auto packStore = [&](float h0, float h1v, unsigned short* dh, unsigned short* dl) {
        half2f hh = __builtin_amdgcn_cvt_pkrtz(h0, h1v);
        half2f ll = __builtin_amdgcn_cvt_pkrtz((h0 - (float)hh[0]) * LS,
                                               (h1v - (float)hh[1]) * LS);
        unsigned uh = h2u(hh), ul = h2u(ll);
        dh[hW] = (unsigned short)uh; dh[hW + 4] = (unsigned short)(uh >> 16);
        dl[hW] = (unsigned short)ul; dl[hW + 4] = (unsigned short)(ul >> 16);
    };

    __syncthreads();  // P1: x(0), x(1), zeroed h visible

    // ---- prologue: gates1(0) = Wih0 @ x(0)  (h1 init = 0) ------------------
    {
        floatx4 aH[2] = {}, aL[2] = {};
#pragma unroll
        for (int ks = 0; ks < 5; ++ks) {
            const int off = l15 * SKX + ks * 32 + quad * 8;
            half8 xh = *(const half8*)(sXh + off);
            half8 xl = *(const half8*)(sXl + off);
#pragma unroll
            for (int mt = 0; mt < 2; ++mt) {
                aH[mt] = __builtin_amdgcn_mfma_f32_16x16x32_f16(bX[ks][mt][0], xh, aH[mt], 0, 0, 0);
                aL[mt] = __builtin_amdgcn_mfma_f32_16x16x32_f16(bX[ks][mt][1], xh, aL[mt], 0, 0, 0);
                aL[mt] = __builtin_amdgcn_mfma_f32_16x16x32_f16(bX[ks][mt][0], xl, aL[mt], 0, 0, 0);
            }
        }
        float hv[2];
#pragma unroll
        for (int mt = 0; mt < 2; ++mt) {
            float gI = fmaf(ILS, aL[mt][0], aH[mt][0]);
            float gF = fmaf(ILS, aL[mt][1], aH[mt][1]);
            float gG = fmaf(ILS, aL[mt][2], aH[mt][2]);
            float gO = fmaf(ILS, aL[mt][3], aH[mt][3]);
            c1[mt] = sigm_(gF) * c1[mt] + sigm_(gI) * tanh_(gG);
            hv[mt] = sigm_(gO) * tanh_(c1[mt]);
        }
        packStore(hv[0], hv[1], sH[0][0][0], sH[0][0][1]);  // h1(0) -> parity 0
    }
    __syncthreads();  // P2: h1(0) visible (h2(-1)=0 already)

    // ---- main skewed loop: iter i -> gates1(i+1) & gates2(i), ONE barrier --
    for (int i = 0; i < Tn - 1; ++i) {
        float2 xr[5];
        const bool pf = (i + 2 < Tn);
        if (pf) {
#pragma unroll
            for (int r = 0; r < 5; ++r) {
                xr[r] = act[r] ? *(const float2*)xp[r] : make_float2(0.f, 0.f);
                xp[r] += Fn;
            }
        }
        const int par = i & 1;
        const unsigned short* bxh = sXh + ((i + 1) & 1) * (16 * SKX);
        const unsigned short* bxl = sXl + ((i + 1) & 1) * (16 * SKX);
        half8 f1h = *(const half8*)(sH[par][0][0] + hOffR);
        half8 f1l = *(const half8*)(sH[par][0][1] + hOffR);
        half8 f2h = *(const half8*)(sH[par][1][0] + hOffR);
        half8 f2l = *(const half8*)(sH[par][1][1] + hOffR);
        floatx4 a1H[2] = {}, a1L[2] = {}, a2H[2] = {}, a2L[2] = {};
#pragma unroll
        for (int ks = 0; ks < 5; ++ks) {
            const int off = l15 * SKX + ks * 32 + quad * 8;
            half8 xh = *(const half8*)(bxh + off);
            half8 xl = *(const half8*)(bxl + off);
#pragma unroll
            for (int mt = 0; mt < 2; ++mt) {
                a1H[mt] = __builtin_amdgcn_mfma_f32_16x16x32_f16(bX[ks][mt][0], xh, a1H[mt], 0, 0, 0);
                a1L[mt] = __builtin_amdgcn_mfma_f32_16x16x32_f16(bX[ks][mt][1], xh, a1L[mt], 0, 0, 0);
                a1L[mt] = __builtin_amdgcn_mfma_f32_16x16x32_f16(bX[ks][mt][0], xl, a1L[mt], 0, 0, 0);
            }
        }
#pragma unroll
        for (int mt = 0; mt < 2; ++mt) {
            a1H[mt] = __builtin_amdgcn_mfma_f32_16x16x32_f16(bW[0][mt][0], f1h, a1H[mt], 0, 0, 0);
            a1L[mt] = __builtin_amdgcn_mfma_f32_16x16x32_f16(bW[0][mt][1], f1h, a1L[mt], 0, 0, 0);
            a1L[mt] = __builtin_amdgcn_mfma_f32_16x16x32_f16(bW[0][mt][0], f1l, a1L[mt], 0, 0, 0);
            a2H[mt] = __builtin_amdgcn_mfma_f32_16x16x32_f16(bW[1][mt][0], f1h, a2H[mt], 0, 0, 0);
            a2L[mt] = __builtin_amdgcn_mfma_f32_16x16x32_f16(bW[1][mt][1], f1h, a2L[mt], 0, 0, 0);
            a2L[mt] = __builtin_amdgcn_mfma_f32_16x16x32_f16(bW[1][mt][0], f1l, a2L[mt], 0, 0, 0);
            a2H[mt] = __builtin_amdgcn_mfma_f32_16x16x32_f16(bW[2][mt][0], f2h, a2H[mt], 0, 0, 0);
            a2L[mt] = __builtin_amdgcn_mfma_f32_16x16x32_f16(bW[2][mt][1], f2h, a2L[mt], 0, 0, 0);
            a2L[mt] = __builtin_amdgcn_mfma_f32_16x16x32_f16(bW[2][mt][0], f2l, a2L[mt], 0, 0, 0);
        }
        // in-register cell updates: layer 2 (step i), layer 1 (step i+1)
        float h1v[2], h2v[2];
#pragma unroll
        for (int mt = 0; mt < 2; ++mt) {
            float gI = fmaf(ILS, a2L[mt][0], a2H[mt][0]);
            float gF = fmaf(ILS, a2L[mt][1], a2H[mt][1]);
            float gG = fmaf(ILS, a2L[mt][2], a2H[mt][2]);
            float gO = fmaf(ILS, a2L[mt][3], a2H[mt][3]);
            c2[mt] = sigm_(gF) * c2[mt] + sigm_(gI) * tanh_(gG);
            h2v[mt] = sigm_(gO) * tanh_(c2[mt]);
            gI = fmaf(ILS, a1L[mt][0], a1H[mt][0]);
            gF = fmaf(ILS, a1L[mt][1], a1H[mt][1]);
            gG = fmaf(ILS, a1L[mt][2], a1H[mt][2]);
            gO = fmaf(ILS, a1L[mt][3], a1H[mt][3]);
            c1[mt] = sigm_(gF) * c1[mt] + sigm_(gI) * tanh_(gG);
            h1v[mt] = sigm_(gO) * tanh_(c1[mt]);
        }
        packStore(h1v[0], h1v[1], sH[par ^ 1][0][0], sH[par ^ 1][0][1]);
        packStore(h2v[0], h2v[1], sH[par ^ 1][1][0], sH[par ^ 1][1][1]);
        if (pf) stage(xr, i & 1);  // x(i+2) -> buf[i&1]; last read was x(i), 1 barrier ago
        __syncthreads();  // the ONE barrier: new h + staged x visible
    }

    // ---- epilogue: gates2(T-1), final layer-2 update (c only) --------------
    {
        const int par = (Tn - 1) & 1;
        half8 f1h = *(const half8*)(sH[par][0][0] + hOffR);
        half8 f1l = *(const half8*)(sH[par][0][1] + hOffR);
        half8 f2h = *(const half8*)(sH[par][1][0] + hOffR);
        half8 f2l = *(const half8*)(sH[par][1][1] + hOffR);
        floatx4 aH[2] = {}, aL[2] = {};
#pragma unroll
        for (int mt = 0; mt < 2; ++mt) {
            aH[mt] = __builtin_amdgcn_mfma_f32_16x16x32_f16(bW[1][mt][0], f1h, aH[mt], 0, 0, 0);
            aL[mt] = __builtin_amdgcn_mfma_f32_16x16x32_f16(bW[1][mt][1], f1h, aL[mt], 0, 0, 0);
            aL[mt] = __builtin_amdgcn_mfma_f32_16x16x32_f16(bW[1][mt][0], f1l, aL[mt], 0, 0, 0);
            aH[mt] = __builtin_amdgcn_mfma_f32_16x16x32_f16(bW[2][mt][0], f2h, aH[mt], 0, 0, 0);
            aL[mt] = __builtin_amdgcn_mfma_f32_16x16x32_f16(bW[2][mt][1], f2h, aL[mt], 0, 0, 0);
            aL[mt] = __builtin_amdgcn_mfma_f32_16x16x32_f16(bW[2][mt][0], f2l, aL[mt], 0, 0, 0);
        }
#pragma unroll
        for (int mt = 0; mt < 2; ++mt) {
            float gI = fmaf(ILS, aL[mt][0], aH[mt][0]);
            float gF = fmaf(ILS, aL[mt][1], aH[mt][1]);
            float gG = fmaf(ILS, aL[mt][2], aH[mt][2]);
            c2[mt] = sigm_(gF) * c2[mt] + sigm_(gI) * tanh_(gG);
        }
    }

    // ---- head on final c1, c2: y = relu(c @ W1^T + b1) @ W2^T --------------
    float* sC = (float*)sXh;  // [2][16][33]; x buffers are dead now
#pragma unroll
    for (int mt = 0; mt < 2; ++mt) {
        sC[l15 * 33 + wave * 8 + mt * 4 + quad] = c1[mt];
        sC[528 + l15 * 33 + wave * 8 + mt * 4 + quad] = c2[mt];
    }
    __syncthreads();
    if (tid < 32) {
        int l = tid >> 4, b = tid & 15;
        const float* cc = sC + l * 528 + b * 33;
        float y = 0.f;
#pragma unroll 1
        for (int q = 0; q < 16; ++q) {
            float s = b1[q];
#pragma unroll
            for (int j = 0; j < 32; ++j) s = fmaf(cc[j], W1[q * 32 + j], s);
            y = fmaf(fmaxf(s, 0.f), W2[q], y);
        }
        out[l * Bn + bBase + b] = y;
    }
}

extern "C" void kernel_launch(void* const* d_in, const int* in_sizes, int n_in,
                              void* d_out, int out_size, void* d_ws, size_t ws_size,
                              hipStream_t stream) {
    const float* x    = (const float*)d_in[0];
    const float* Wih0 = (const float*)d_in[1];
    const float* Whh0 = (const float*)d_in[2];
    const float* Wih1 = (const float*)d_in[3];
    const float* Whh1 = (const float*)d_in[4];
    const float* W1   = (const float*)d_in[5];
    const float* b1   = (const float*)d_in[6];
    const float* W2   = (const float*)d_in[7];
    float* out = (float*)d_out;

    lstm2_fused_kernel<<<Bn / 16, 256, 0, stream>>>(x, Wih0, Whh0, Wih1, Whh1,
                                                    W1, b1, W2, out);
}